// Round 1
// baseline (450.635 us; speedup 1.0000x reference)
//
#include <hip/hip_runtime.h>

#define D 128          // D_IN == D_OUT == 128
#define NB_MAX 1600    // max coarse buckets (ceil(n_nodes/64))
#define T_TILES 256    // edge tiles for the counting split

// round-to-nearest-even fp32 -> bf16 (as low 16 bits)
__device__ __forceinline__ unsigned bf16_rne(float f) {
    const unsigned u = __float_as_uint(f);
    return (u + 0x7FFFu + ((u >> 16) & 1u)) >> 16;
}
__device__ __forceinline__ float bf_lo(unsigned u) { return __uint_as_float(u << 16); }
__device__ __forceinline__ float bf_hi(unsigned u) { return __uint_as_float(u & 0xFFFF0000u); }

// -------- Stage 1: support = x @ W  (fp32 compute, bf16 output) ------------
// 128x128 tile per 256-thread block, 8x8 outputs/thread, k-slabs of 32.
// All LDS reads are b128:
//   x slab [128][32] stored with per-8-row rotate swizzle (col' = (k + 8*(r>>3))&31)
//     -> compute reads hit 4 distinct bank-quads (conflict-free).
//   W slab [32][128] row-major; each thread reads col quads {4cg, 64+4cg}
//     -> 16 lanes at stride-4-words = 2-way bank aliasing (free).
// fp32 accumulation remains strictly k-ascending per output element, so the
// bf16-rounded support is bit-identical to the previous version.
__global__ __launch_bounds__(256, 4) void gcn_gemm(const float* __restrict__ x,
                                                   const float* __restrict__ w,
                                                   unsigned* __restrict__ support, // bf16x2 units
                                                   int n_nodes) {
    __shared__ float xs[128][32];   // 16 KB, swizzled cols
    __shared__ float ws[32][128];   // 16 KB
    const int t = threadIdx.x;
    const int rg = t >> 4;          // [0,16): rows rg*8 .. rg*8+7
    const int cg = t & 15;          // [0,16): cols 4cg..4cg+3 and 64+4cg..64+4cg+3
    const long row_base = (long)blockIdx.x * 128;

    float4 acc[8][2];
#pragma unroll
    for (int j = 0; j < 8; ++j) {
        acc[j][0] = make_float4(0.f, 0.f, 0.f, 0.f);
        acc[j][1] = make_float4(0.f, 0.f, 0.f, 0.f);
    }

    for (int s = 0; s < 4; ++s) {
        const int k0 = s * 32;
        // stage W slab (contiguous 16 KB, coalesced)
        {
            const float4* w4 = (const float4*)(w + (long)k0 * D);
            float4* wl = (float4*)&ws[0][0];
#pragma unroll
            for (int i = 0; i < 4; ++i) wl[t + 256 * i] = w4[t + 256 * i];
        }
        // stage x slab: 128 rows x 32 k, rotate-swizzled
        {
#pragma unroll
            for (int i = 0; i < 4; ++i) {
                const int f = t + 256 * i;   // [0,1024) float4s
                const int r = f >> 3;
                const int jj = f & 7;
                long gr = row_base + r;
                if (gr >= n_nodes) gr = n_nodes - 1;   // clamp tail (stores guarded)
                const float4 v = ((const float4*)(x + gr * D + k0))[jj];
                const int cs = (jj * 4 + 8 * (r >> 3)) & 31;
                ((float4*)&xs[r][0])[cs >> 2] = v;
            }
        }
        __syncthreads();

        const int xrot = 8 * rg;   // thread's rows all have r>>3 == rg
#pragma unroll 1
        for (int kk = 0; kk < 32; kk += 4) {
            float4 wq[4][2];
#pragma unroll
            for (int d = 0; d < 4; ++d) {
                const float4* wr = (const float4*)&ws[kk + d][0];
                wq[d][0] = wr[cg];
                wq[d][1] = wr[cg + 16];
            }
            const int xi = ((kk + xrot) & 31) >> 2;
#pragma unroll
            for (int j = 0; j < 8; ++j) {
                const float4 xv = ((const float4*)&xs[rg * 8 + j][0])[xi];
#define FMA4(A, S, W) A.x += S * W.x; A.y += S * W.y; A.z += S * W.z; A.w += S * W.w
                FMA4(acc[j][0], xv.x, wq[0][0]); FMA4(acc[j][1], xv.x, wq[0][1]);
                FMA4(acc[j][0], xv.y, wq[1][0]); FMA4(acc[j][1], xv.y, wq[1][1]);
                FMA4(acc[j][0], xv.z, wq[2][0]); FMA4(acc[j][1], xv.z, wq[2][1]);
                FMA4(acc[j][0], xv.w, wq[3][0]); FMA4(acc[j][1], xv.w, wq[3][1]);
#undef FMA4
            }
        }
        __syncthreads();
    }

#pragma unroll
    for (int j = 0; j < 8; ++j) {
        const long r = row_base + rg * 8 + j;
        if (r < n_nodes) {
            uint2 p0, p1;
            p0.x = bf16_rne(acc[j][0].x) | (bf16_rne(acc[j][0].y) << 16);
            p0.y = bf16_rne(acc[j][0].z) | (bf16_rne(acc[j][0].w) << 16);
            p1.x = bf16_rne(acc[j][1].x) | (bf16_rne(acc[j][1].y) << 16);
            p1.y = bf16_rne(acc[j][1].z) | (bf16_rne(acc[j][1].w) << 16);
            ((uint2*)support)[r * 32 + cg] = p0;        // cols 4cg..4cg+3
            ((uint2*)support)[r * 32 + 16 + cg] = p1;   // cols 64+4cg..
        }
    }
}

// -------- Stage 2a: per-tile coarse-bucket histogram (raw counts) ----------
__global__ __launch_bounds__(1024) void gcn_tile_hist(const int* __restrict__ erow,
                                                      int* __restrict__ M,
                                                      int n_edges, int tile_sz, int nb) {
    __shared__ int h[NB_MAX];
    const int t = threadIdx.x;
    for (int i = t; i < nb; i += 1024) h[i] = 0;
    __syncthreads();
    const int beg = blockIdx.x * tile_sz;
    const int end = min(beg + tile_sz, n_edges);
    for (int e = beg + t; e < end; e += 1024)
        atomicAdd(&h[erow[e] >> 6], 1);
    __syncthreads();
    int* Mrow = M + (long)blockIdx.x * nb;
    for (int i = t; i < nb; i += 1024) Mrow[i] = h[i];
}

// -------- Stage 2b: vertical exclusive scan per bucket; totals out ---------
__global__ __launch_bounds__(256) void gcn_tile_offsets(int* __restrict__ M,
                                                        int* __restrict__ totals,
                                                        int nb) {
    const int cb = blockIdx.x * 256 + threadIdx.x;
    if (cb >= nb) return;
    int running = 0;
#pragma unroll 8
    for (int tt = 0; tt < T_TILES; ++tt) {
        int* p = M + (long)tt * nb + cb;   // coalesced across threads
        const int c = *p;
        *p = running;
        running += c;
    }
    totals[cb] = running;
}

// -------- Stage 2c: exclusive scan of bucket totals -> base[0..nb] ---------
__global__ __launch_bounds__(1024) void gcn_scan_base(const int* __restrict__ totals,
                                                      int* __restrict__ base, int nb) {
    __shared__ int sdata[1024];
    const int t = threadIdx.x;
    const int chunk = (nb + 1023) >> 10;
    const int beg = min(t * chunk, nb);
    const int end = min(beg + chunk, nb);

    int sum = 0;
    for (int i = beg; i < end; ++i) sum += totals[i];
    sdata[t] = sum;
    __syncthreads();
    for (int off = 1; off < 1024; off <<= 1) {
        const int v = (t >= off) ? sdata[t - off] : 0;
        __syncthreads();
        sdata[t] += v;
        __syncthreads();
    }
    int running = sdata[t] - sum;
    if (t == 1023) base[nb] = sdata[1023];
    for (int i = beg; i < end; ++i) {
        const int c = totals[i];
        base[i] = running;
        running += c;
    }
}

// -------- Stage 2d: scatter edges into bucket-grouped tmp ------------------
__global__ __launch_bounds__(1024) void gcn_split(const int* __restrict__ erow,
                                                  const int* __restrict__ ecol,
                                                  const float* __restrict__ eval,
                                                  const int* __restrict__ M,
                                                  const int* __restrict__ base,
                                                  int2* __restrict__ tmp,
                                                  int n_edges, int tile_sz, int nb) {
    __shared__ int off[NB_MAX];
    const int t = threadIdx.x;
    const int* Mrow = M + (long)blockIdx.x * nb;
    for (int i = t; i < nb; i += 1024) off[i] = Mrow[i] + base[i];
    __syncthreads();
    const int beg = blockIdx.x * tile_sz;
    const int end = min(beg + tile_sz, n_edges);
    for (int e = beg + t; e < end; e += 1024) {
        const int r = erow[e];
        const int pos = atomicAdd(&off[r >> 6], 1);
        const unsigned key = ((unsigned)(r & 63) << 17) | (unsigned)ecol[e];
        tmp[pos] = make_int2((int)key, __float_as_int(eval[e]));
    }
}

// -------- Stage 2e: per-bucket counting sort -> exact CSR + rp -------------
__global__ __launch_bounds__(256) void gcn_bucket_fill(const int2* __restrict__ tmp,
                                                       const int* __restrict__ base,
                                                       int2* __restrict__ packed,
                                                       int* __restrict__ rp,
                                                       int n_nodes) {
    __shared__ int hist[64];
    __shared__ int offs[64];
    const int t = threadIdx.x;
    const int cb = blockIdx.x;
    const int start = base[cb];
    const int stop = base[cb + 1];

    if (t < 64) hist[t] = 0;
    __syncthreads();
    for (int i = start + t; i < stop; i += 256)
        atomicAdd(&hist[(unsigned)tmp[i].x >> 17], 1);
    __syncthreads();
    if (t == 0) {
        int run = 0;
#pragma unroll
        for (int i = 0; i < 64; ++i) { offs[i] = run; run += hist[i]; }
    }
    __syncthreads();
    if (t < 64) {
        const int r = cb * 64 + t;
        if (r < n_nodes) rp[r] = start + offs[t];
    }
    __syncthreads();
    for (int i = start + t; i < stop; i += 256) {
        const int2 ed = tmp[i];
        const int rl = (int)((unsigned)ed.x >> 17);
        const int pos = start + atomicAdd(&offs[rl], 1);
        packed[pos] = make_int2(ed.x & 0x1FFFF, ed.y);
    }
}

// -------- Stage 3: out[r] = bias + sum v_e * support[c_e] ------------------
// One wave per row; 4 edges per VMEM instruction (4 groups of 16 lanes, each
// lane loads uint4 = 8 bf16 cols). NEW: depth-8 gather prefetch — issue up to
// 8 independent support-row gathers before consuming any (static pv[8]
// indexing, wave-uniform guards). Accumulation order per batch is unchanged
// -> bit-identical output.
__global__ __launch_bounds__(512, 5) void gcn_aggregate(const uint4* __restrict__ support4,
                                                        const int2* __restrict__ packed,
                                                        const int* __restrict__ rp,
                                                        const float* __restrict__ bias,
                                                        float* __restrict__ out,
                                                        int n_nodes, int n_edges) {
    const int t = threadIdx.x;
    const int lane = t & 63;
    const int sub = lane & 15;   // which 16B slice of the row
    const int g = lane >> 4;     // which edge of the 4-edge batch
    const int r = blockIdx.x * 8 + (t >> 6);   // 8 waves per block
    if (r >= n_nodes) return;

    const int start = rp[r];
    const int end = (r + 1 < n_nodes) ? rp[r + 1] : n_edges;

    float acc[8];
#pragma unroll
    for (int k = 0; k < 8; ++k) acc[k] = 0.f;

    for (int b = start; b < end; b += 64) {
        const int nn = min(64, end - b);
        int2 ed = make_int2(0, 0);             // c=0 for pad lanes: safe row
        if (lane < nn) ed = packed[b + lane];  // coalesced 8B/lane
        const int nbat = (nn + 3) >> 2;        // wave-uniform
        for (int i0 = 0; i0 < nbat; i0 += 8) {
            const int nb8 = min(8, nbat - i0); // wave-uniform
            uint4 pv[8];
            float vv[8];
            // issue phase: up to 8 gathers in flight
#pragma unroll
            for (int i = 0; i < 8; ++i) {
                if (i < nb8) {
                    const int idx = (i0 + i) * 4 + g;
                    const int c = __shfl(ed.x, idx, 64);
                    float v = __int_as_float(__shfl(ed.y, idx, 64));
                    if (idx >= nn) v = 0.f;
                    vv[i] = v;
                    pv[i] = support4[(long)c * 16 + sub];  // 1KB/wave-instr
                }
            }
            // consume phase
#pragma unroll
            for (int i = 0; i < 8; ++i) {
                if (i < nb8) {
                    acc[0] += vv[i] * bf_lo(pv[i].x);
                    acc[1] += vv[i] * bf_hi(pv[i].x);
                    acc[2] += vv[i] * bf_lo(pv[i].y);
                    acc[3] += vv[i] * bf_hi(pv[i].y);
                    acc[4] += vv[i] * bf_lo(pv[i].z);
                    acc[5] += vv[i] * bf_hi(pv[i].z);
                    acc[6] += vv[i] * bf_lo(pv[i].w);
                    acc[7] += vv[i] * bf_hi(pv[i].w);
                }
            }
        }
    }

    // Reduce the 4 edge-groups (lanes sub, sub+16, sub+32, sub+48)
#pragma unroll
    for (int k = 0; k < 8; ++k) {
        acc[k] += __shfl_xor(acc[k], 16, 64);
        acc[k] += __shfl_xor(acc[k], 32, 64);
    }

    if (g == 0) {   // lanes 0..15 write cols sub*8 .. sub*8+7
        const float4 b0 = ((const float4*)bias)[sub * 2];
        const float4 b1 = ((const float4*)bias)[sub * 2 + 1];
        float4 o0 = make_float4(acc[0] + b0.x, acc[1] + b0.y, acc[2] + b0.z, acc[3] + b0.w);
        float4 o1 = make_float4(acc[4] + b1.x, acc[5] + b1.y, acc[6] + b1.z, acc[7] + b1.w);
        float4* orow = (float4*)(out + (long)r * D);
        orow[sub * 2] = o0;
        orow[sub * 2 + 1] = o1;
    }
}

extern "C" void kernel_launch(void* const* d_in, const int* in_sizes, int n_in,
                              void* d_out, int out_size, void* d_ws, size_t ws_size,
                              hipStream_t stream) {
    const float* x    = (const float*)d_in[0];
    const float* w    = (const float*)d_in[1];
    const float* bias = (const float*)d_in[2];
    const int* erow   = (const int*)d_in[3];
    const int* ecol   = (const int*)d_in[4];
    const float* eval = (const float*)d_in[5];

    const int n_nodes = in_sizes[0] / D;   // 100000
    const int n_edges = in_sizes[3];       // 3200000
    const int nb = (n_nodes + 63) >> 6;    // 1563 coarse buckets
    const int tile_sz = (n_edges + T_TILES - 1) / T_TILES;

    // Persistent workspace: support(bf16, 25.6MB) | packed | rp
    char* ws = (char*)d_ws;
    unsigned* support = (unsigned*)ws;     // n_nodes * 64 bf16x2 words
    size_t off = (size_t)n_nodes * (D / 2) * sizeof(unsigned);
    int2* packed = (int2*)(ws + off);
    off += (size_t)n_edges * sizeof(int2);
    int* rp = (int*)(ws + off);

    // Transient buffers in d_out (dead before aggregate writes it)
    char* ob = (char*)d_out;
    int2* tmp = (int2*)ob;
    size_t ooff = (size_t)n_edges * sizeof(int2);
    int* M = (int*)(ob + ooff);
    ooff += (size_t)T_TILES * nb * sizeof(int);
    int* totals = (int*)(ob + ooff);
    ooff += (size_t)(nb + 1) * sizeof(int);
    int* base = (int*)(ob + ooff);

    float* out = (float*)d_out;

    // 1. support = x @ W (bf16 output), 128-row tiles
    gcn_gemm<<<(n_nodes + 127) / 128, 256, 0, stream>>>(x, w, support, n_nodes);

    // 2. Two-phase counting split -> exact CSR (packed, rp)
    gcn_tile_hist<<<T_TILES, 1024, 0, stream>>>(erow, M, n_edges, tile_sz, nb);
    gcn_tile_offsets<<<(nb + 255) / 256, 256, 0, stream>>>(M, totals, nb);
    gcn_scan_base<<<1, 1024, 0, stream>>>(totals, base, nb);
    gcn_split<<<T_TILES, 1024, 0, stream>>>(erow, ecol, eval, M, base, tmp,
                                            n_edges, tile_sz, nb);
    gcn_bucket_fill<<<nb, 256, 0, stream>>>(tmp, base, packed, rp, n_nodes);

    // 3. Gather-aggregate: one wave per row, depth-8 prefetched dwordx4 gathers
    gcn_aggregate<<<(n_nodes + 7) / 8, 512, 0, stream>>>(
        (const uint4*)support, packed, rp, bias, out, n_nodes, n_edges);
}

// Round 2
// 412.219 us; speedup vs baseline: 1.0932x; 1.0932x over previous
//
#include <hip/hip_runtime.h>

#define D 128          // D_IN == D_OUT == 128
#define NB_MAX 1600    // max coarse buckets (ceil(n_nodes/64))
#define T_TILES 256    // edge tiles for the counting split

typedef unsigned u32x4 __attribute__((ext_vector_type(4)));

// round-to-nearest-even fp32 -> bf16 (as low 16 bits)
__device__ __forceinline__ unsigned bf16_rne(float f) {
    const unsigned u = __float_as_uint(f);
    return (u + 0x7FFFu + ((u >> 16) & 1u)) >> 16;
}
__device__ __forceinline__ float bf_lo(unsigned u) { return __uint_as_float(u << 16); }
__device__ __forceinline__ float bf_hi(unsigned u) { return __uint_as_float(u & 0xFFFF0000u); }

// -------- Stage 1: support = x @ W  (fp32 compute, bf16 output) ------------
// 128x128 tile per 256-thread block, 8x8 outputs/thread, k-slabs of 32.
// All LDS reads are b128 (rotate-swizzled x slab; W col quads 2-way = free).
// launch_bounds(256,2): 256-VGPR budget -- the (256,4)=128-reg cap in the
// previous round likely spilled acc(64)+wq(32)+staging.
__global__ __launch_bounds__(256, 2) void gcn_gemm(const float* __restrict__ x,
                                                   const float* __restrict__ w,
                                                   unsigned* __restrict__ support, // bf16x2 units
                                                   int n_nodes) {
    __shared__ float xs[128][32];   // 16 KB, swizzled cols
    __shared__ float ws[32][128];   // 16 KB
    const int t = threadIdx.x;
    const int rg = t >> 4;          // [0,16): rows rg*8 .. rg*8+7
    const int cg = t & 15;          // [0,16): cols 4cg..4cg+3 and 64+4cg..64+4cg+3
    const long row_base = (long)blockIdx.x * 128;

    float4 acc[8][2];
#pragma unroll
    for (int j = 0; j < 8; ++j) {
        acc[j][0] = make_float4(0.f, 0.f, 0.f, 0.f);
        acc[j][1] = make_float4(0.f, 0.f, 0.f, 0.f);
    }

    for (int s = 0; s < 4; ++s) {
        const int k0 = s * 32;
        // stage W slab (contiguous 16 KB, coalesced)
        {
            const float4* w4 = (const float4*)(w + (long)k0 * D);
            float4* wl = (float4*)&ws[0][0];
#pragma unroll
            for (int i = 0; i < 4; ++i) wl[t + 256 * i] = w4[t + 256 * i];
        }
        // stage x slab: 128 rows x 32 k, rotate-swizzled
        {
#pragma unroll
            for (int i = 0; i < 4; ++i) {
                const int f = t + 256 * i;   // [0,1024) float4s
                const int r = f >> 3;
                const int jj = f & 7;
                long gr = row_base + r;
                if (gr >= n_nodes) gr = n_nodes - 1;   // clamp tail (stores guarded)
                const float4 v = ((const float4*)(x + gr * D + k0))[jj];
                const int cs = (jj * 4 + 8 * (r >> 3)) & 31;
                ((float4*)&xs[r][0])[cs >> 2] = v;
            }
        }
        __syncthreads();

        const int xrot = 8 * rg;   // thread's rows all have r>>3 == rg
#pragma unroll 1
        for (int kk = 0; kk < 32; kk += 4) {
            float4 wq[4][2];
#pragma unroll
            for (int d = 0; d < 4; ++d) {
                const float4* wr = (const float4*)&ws[kk + d][0];
                wq[d][0] = wr[cg];
                wq[d][1] = wr[cg + 16];
            }
            const int xi = ((kk + xrot) & 31) >> 2;
#pragma unroll
            for (int j = 0; j < 8; ++j) {
                const float4 xv = ((const float4*)&xs[rg * 8 + j][0])[xi];
#define FMA4(A, S, W) A.x += S * W.x; A.y += S * W.y; A.z += S * W.z; A.w += S * W.w
                FMA4(acc[j][0], xv.x, wq[0][0]); FMA4(acc[j][1], xv.x, wq[0][1]);
                FMA4(acc[j][0], xv.y, wq[1][0]); FMA4(acc[j][1], xv.y, wq[1][1]);
                FMA4(acc[j][0], xv.z, wq[2][0]); FMA4(acc[j][1], xv.z, wq[2][1]);
                FMA4(acc[j][0], xv.w, wq[3][0]); FMA4(acc[j][1], xv.w, wq[3][1]);
#undef FMA4
            }
        }
        __syncthreads();
    }

#pragma unroll
    for (int j = 0; j < 8; ++j) {
        const long r = row_base + rg * 8 + j;
        if (r < n_nodes) {
            uint2 p0, p1;
            p0.x = bf16_rne(acc[j][0].x) | (bf16_rne(acc[j][0].y) << 16);
            p0.y = bf16_rne(acc[j][0].z) | (bf16_rne(acc[j][0].w) << 16);
            p1.x = bf16_rne(acc[j][1].x) | (bf16_rne(acc[j][1].y) << 16);
            p1.y = bf16_rne(acc[j][1].z) | (bf16_rne(acc[j][1].w) << 16);
            ((uint2*)support)[r * 32 + cg] = p0;        // cols 4cg..4cg+3
            ((uint2*)support)[r * 32 + 16 + cg] = p1;   // cols 64+4cg..
        }
    }
}

// -------- Stage 2a: per-tile coarse-bucket histogram (raw counts) ----------
__global__ __launch_bounds__(1024) void gcn_tile_hist(const int* __restrict__ erow,
                                                      int* __restrict__ M,
                                                      int n_edges, int tile_sz, int nb) {
    __shared__ int h[NB_MAX];
    const int t = threadIdx.x;
    for (int i = t; i < nb; i += 1024) h[i] = 0;
    __syncthreads();
    const int beg = blockIdx.x * tile_sz;
    const int end = min(beg + tile_sz, n_edges);
    for (int e = beg + t; e < end; e += 1024)
        atomicAdd(&h[erow[e] >> 6], 1);
    __syncthreads();
    int* Mrow = M + (long)blockIdx.x * nb;
    for (int i = t; i < nb; i += 1024) Mrow[i] = h[i];
}

// -------- Stage 2b: vertical exclusive scan per bucket; totals out ---------
__global__ __launch_bounds__(256) void gcn_tile_offsets(int* __restrict__ M,
                                                        int* __restrict__ totals,
                                                        int nb) {
    const int cb = blockIdx.x * 256 + threadIdx.x;
    if (cb >= nb) return;
    int running = 0;
#pragma unroll 8
    for (int tt = 0; tt < T_TILES; ++tt) {
        int* p = M + (long)tt * nb + cb;   // coalesced across threads
        const int c = *p;
        *p = running;
        running += c;
    }
    totals[cb] = running;
}

// -------- Stage 2c: exclusive scan of bucket totals -> base[0..nb] ---------
__global__ __launch_bounds__(1024) void gcn_scan_base(const int* __restrict__ totals,
                                                      int* __restrict__ base, int nb) {
    __shared__ int sdata[1024];
    const int t = threadIdx.x;
    const int chunk = (nb + 1023) >> 10;
    const int beg = min(t * chunk, nb);
    const int end = min(beg + chunk, nb);

    int sum = 0;
    for (int i = beg; i < end; ++i) sum += totals[i];
    sdata[t] = sum;
    __syncthreads();
    for (int off = 1; off < 1024; off <<= 1) {
        const int v = (t >= off) ? sdata[t - off] : 0;
        __syncthreads();
        sdata[t] += v;
        __syncthreads();
    }
    int running = sdata[t] - sum;
    if (t == 1023) base[nb] = sdata[1023];
    for (int i = beg; i < end; ++i) {
        const int c = totals[i];
        base[i] = running;
        running += c;
    }
}

// -------- Stage 2d: scatter edges into bucket-grouped tmp ------------------
__global__ __launch_bounds__(1024) void gcn_split(const int* __restrict__ erow,
                                                  const int* __restrict__ ecol,
                                                  const float* __restrict__ eval,
                                                  const int* __restrict__ M,
                                                  const int* __restrict__ base,
                                                  int2* __restrict__ tmp,
                                                  int n_edges, int tile_sz, int nb) {
    __shared__ int off[NB_MAX];
    const int t = threadIdx.x;
    const int* Mrow = M + (long)blockIdx.x * nb;
    for (int i = t; i < nb; i += 1024) off[i] = Mrow[i] + base[i];
    __syncthreads();
    const int beg = blockIdx.x * tile_sz;
    const int end = min(beg + tile_sz, n_edges);
    for (int e = beg + t; e < end; e += 1024) {
        const int r = erow[e];
        const int pos = atomicAdd(&off[r >> 6], 1);
        const unsigned key = ((unsigned)(r & 63) << 17) | (unsigned)ecol[e];
        tmp[pos] = make_int2((int)key, __float_as_int(eval[e]));
    }
}

// -------- Stage 2e: per-bucket counting sort -> exact CSR + rp -------------
__global__ __launch_bounds__(256) void gcn_bucket_fill(const int2* __restrict__ tmp,
                                                       const int* __restrict__ base,
                                                       int2* __restrict__ packed,
                                                       int* __restrict__ rp,
                                                       int n_nodes) {
    __shared__ int hist[64];
    __shared__ int offs[64];
    const int t = threadIdx.x;
    const int cb = blockIdx.x;
    const int start = base[cb];
    const int stop = base[cb + 1];

    if (t < 64) hist[t] = 0;
    __syncthreads();
    for (int i = start + t; i < stop; i += 256)
        atomicAdd(&hist[(unsigned)tmp[i].x >> 17], 1);
    __syncthreads();
    if (t == 0) {
        int run = 0;
#pragma unroll
        for (int i = 0; i < 64; ++i) { offs[i] = run; run += hist[i]; }
    }
    __syncthreads();
    if (t < 64) {
        const int r = cb * 64 + t;
        if (r < n_nodes) rp[r] = start + offs[t];
    }
    __syncthreads();
    for (int i = start + t; i < stop; i += 256) {
        const int2 ed = tmp[i];
        const int rl = (int)((unsigned)ed.x >> 17);
        const int pos = start + atomicAdd(&offs[rl], 1);
        packed[pos] = make_int2(ed.x & 0x1FFFF, ed.y);
    }
}

// -------- Stage 3: out[r] = bias + sum v_e * support[c_e] ------------------
// One wave per row; 4 edges per VMEM instruction (4 groups of 16 lanes, each
// lane loads 16B = 8 bf16 cols). Depth-8 gather MLP, this time FORCED:
//  - issue phase is UNGUARDED: idx=(i0+i)*4+g <= 63 always, so every __shfl
//    is valid; pad lanes carry ed=(0,0) so dummy slots load row 0 (L1-hot)
//    with v=0 -> contribute exactly +0.f. Real-edge accumulation order is
//    unchanged -> numerics identical.
//  - one empty asm volatile with "+v" on all 8 result quads pins the
//    schedule: 8 loads BEFORE the asm, all consumes AFTER it. The compiler
//    cannot re-fuse issue/consume (round-1 failure mode: VGPR=36 proved the
//    guarded loops were merged, leaving 1 load in flight).
__global__ __launch_bounds__(512) void gcn_aggregate(const unsigned* __restrict__ support_u,
                                                     const int2* __restrict__ packed,
                                                     const int* __restrict__ rp,
                                                     const float* __restrict__ bias,
                                                     float* __restrict__ out,
                                                     int n_nodes, int n_edges) {
    const int t = threadIdx.x;
    const int lane = t & 63;
    const int sub = lane & 15;   // which 16B slice of the row
    const int g = lane >> 4;     // which edge of the 4-edge batch
    const int r = blockIdx.x * 8 + (t >> 6);   // 8 waves per block
    if (r >= n_nodes) return;

    const int start = rp[r];
    const int end = (r + 1 < n_nodes) ? rp[r + 1] : n_edges;

    float acc[8];
#pragma unroll
    for (int k = 0; k < 8; ++k) acc[k] = 0.f;

    for (int b = start; b < end; b += 64) {
        const int nn = min(64, end - b);
        int2 ed = make_int2(0, 0);             // c=0,v=0 for pad lanes: safe row 0
        if (lane < nn) ed = packed[b + lane];  // coalesced 8B/lane
        const int nbat = (nn + 3) >> 2;        // wave-uniform, <= 16
        for (int i0 = 0; i0 < nbat; i0 += 8) {
            u32x4 pv0, pv1, pv2, pv3, pv4, pv5, pv6, pv7;
            float vv0, vv1, vv2, vv3, vv4, vv5, vv6, vv7;
#define ISSUE(I, PV, VV)                                                   \
            {                                                              \
                const int idx = (i0 + I) * 4 + g;        /* <= 63 */       \
                const int c = __shfl(ed.x, idx, 64);                       \
                float v = __int_as_float(__shfl(ed.y, idx, 64));           \
                if (idx >= nn) v = 0.f;                                    \
                VV = v;                                                    \
                PV = *(const u32x4*)(support_u + (long)c * 64 + sub * 4);  \
            }
            ISSUE(0, pv0, vv0) ISSUE(1, pv1, vv1) ISSUE(2, pv2, vv2) ISSUE(3, pv3, vv3)
            ISSUE(4, pv4, vv4) ISSUE(5, pv5, vv5) ISSUE(6, pv6, vv6) ISSUE(7, pv7, vv7)
#undef ISSUE
            // schedule pin: all 8 gathers complete here; consumes follow
            asm volatile("" : "+v"(pv0), "+v"(pv1), "+v"(pv2), "+v"(pv3),
                              "+v"(pv4), "+v"(pv5), "+v"(pv6), "+v"(pv7));
#define CONS(PV, VV)                                                       \
            {                                                              \
                acc[0] += VV * bf_lo(PV[0]); acc[1] += VV * bf_hi(PV[0]);  \
                acc[2] += VV * bf_lo(PV[1]); acc[3] += VV * bf_hi(PV[1]);  \
                acc[4] += VV * bf_lo(PV[2]); acc[5] += VV * bf_hi(PV[2]);  \
                acc[6] += VV * bf_lo(PV[3]); acc[7] += VV * bf_hi(PV[3]);  \
            }
            CONS(pv0, vv0) CONS(pv1, vv1) CONS(pv2, vv2) CONS(pv3, vv3)
            CONS(pv4, vv4) CONS(pv5, vv5) CONS(pv6, vv6) CONS(pv7, vv7)
#undef CONS
        }
    }

    // Reduce the 4 edge-groups (lanes sub, sub+16, sub+32, sub+48)
#pragma unroll
    for (int k = 0; k < 8; ++k) {
        acc[k] += __shfl_xor(acc[k], 16, 64);
        acc[k] += __shfl_xor(acc[k], 32, 64);
    }

    if (g == 0) {   // lanes 0..15 write cols sub*8 .. sub*8+7
        const float4 b0 = ((const float4*)bias)[sub * 2];
        const float4 b1 = ((const float4*)bias)[sub * 2 + 1];
        float4 o0 = make_float4(acc[0] + b0.x, acc[1] + b0.y, acc[2] + b0.z, acc[3] + b0.w);
        float4 o1 = make_float4(acc[4] + b1.x, acc[5] + b1.y, acc[6] + b1.z, acc[7] + b1.w);
        float4* orow = (float4*)(out + (long)r * D);
        orow[sub * 2] = o0;
        orow[sub * 2 + 1] = o1;
    }
}

extern "C" void kernel_launch(void* const* d_in, const int* in_sizes, int n_in,
                              void* d_out, int out_size, void* d_ws, size_t ws_size,
                              hipStream_t stream) {
    const float* x    = (const float*)d_in[0];
    const float* w    = (const float*)d_in[1];
    const float* bias = (const float*)d_in[2];
    const int* erow   = (const int*)d_in[3];
    const int* ecol   = (const int*)d_in[4];
    const float* eval = (const float*)d_in[5];

    const int n_nodes = in_sizes[0] / D;   // 100000
    const int n_edges = in_sizes[3];       // 3200000
    const int nb = (n_nodes + 63) >> 6;    // 1563 coarse buckets
    const int tile_sz = (n_edges + T_TILES - 1) / T_TILES;

    // Persistent workspace: support(bf16, 25.6MB) | packed | rp
    char* ws = (char*)d_ws;
    unsigned* support = (unsigned*)ws;     // n_nodes * 64 bf16x2 words
    size_t off = (size_t)n_nodes * (D / 2) * sizeof(unsigned);
    int2* packed = (int2*)(ws + off);
    off += (size_t)n_edges * sizeof(int2);
    int* rp = (int*)(ws + off);

    // Transient buffers in d_out (dead before aggregate writes it)
    char* ob = (char*)d_out;
    int2* tmp = (int2*)ob;
    size_t ooff = (size_t)n_edges * sizeof(int2);
    int* M = (int*)(ob + ooff);
    ooff += (size_t)T_TILES * nb * sizeof(int);
    int* totals = (int*)(ob + ooff);
    ooff += (size_t)(nb + 1) * sizeof(int);
    int* base = (int*)(ob + ooff);

    float* out = (float*)d_out;

    // 1. support = x @ W (bf16 output), 128-row tiles
    gcn_gemm<<<(n_nodes + 127) / 128, 256, 0, stream>>>(x, w, support, n_nodes);

    // 2. Two-phase counting split -> exact CSR (packed, rp)
    gcn_tile_hist<<<T_TILES, 1024, 0, stream>>>(erow, M, n_edges, tile_sz, nb);
    gcn_tile_offsets<<<(nb + 255) / 256, 256, 0, stream>>>(M, totals, nb);
    gcn_scan_base<<<1, 1024, 0, stream>>>(totals, base, nb);
    gcn_split<<<T_TILES, 1024, 0, stream>>>(erow, ecol, eval, M, base, tmp,
                                            n_edges, tile_sz, nb);
    gcn_bucket_fill<<<nb, 256, 0, stream>>>(tmp, base, packed, rp, n_nodes);

    // 3. Gather-aggregate: one wave per row, forced depth-8 dwordx4 gathers
    gcn_aggregate<<<(n_nodes + 7) / 8, 512, 0, stream>>>(
        (const unsigned*)support, packed, rp, bias, out, n_nodes, n_edges);
}